// Round 3
// baseline (265.126 us; speedup 1.0000x reference)
//
#include <hip/hip_runtime.h>
#include <hip/hip_bf16.h>
#include <stdint.h>

// y = x @ W^T + bias ; x:(32,4096) f32, W:(11008,4096) f32, bias:(11008) f32
//
// Round-2 finding: dur_us (254) is dominated by harness reset cost — a per-
// iteration 688 MB workspace-poison fill (~105 us, visible as the top-5
// fillBufferAligned dispatches) plus restore dispatches. The gemm itself is
// < 104 us in BOTH the VGPR-load and async-LDS versions (absent from top-5).
//
// This version: single fused kernel, ZERO workspace usage (the only remaining
// lever on the fill cost). The cvt pass is folded into the gemm: A-fragments
// load directly from fp32 x (512 KB, L2-resident; entire x re-read per block
// from L2/L3, ~10 us aggregate at L2 BW) and are converted with the same RNE
// pk2bf at use -> bit-identical numerics to the two-kernel version.
//
// W streaming (unchanged, proven): per-wave private K-slice of 1024, 8 chunks
// of 128 k staged via async global_load_lds into a double-buffered LDS ring,
// counted s_waitcnt (never 0 mid-loop), no barriers in the K-loop, T2 both-
// sides XOR swizzle (LDS linear for the DMA, global source pre-swizzled,
// ds_read applies the same XOR). vmcnt stream is now 24 ops/chunk:
// 8 W-DMAs + 16 fp32 A-loads; vmcnt(24) == "chunk c fully landed".

#define M 32
#define N 11008
#define K 4096
#define BN 16
#define WKSLICE (K / 4)           // 1024 k per wave
#define CK 128                    // k floats per chunk per wave
#define NCHUNK (WKSLICE / CK)     // 8 chunks
#define CHFL (16 * CK)            // floats per chunk buffer (2048 = 8 KB)

typedef __attribute__((ext_vector_type(8))) short bf16x8;
typedef __attribute__((ext_vector_type(4))) float f32x4;
typedef unsigned int u32;

// two fp32 -> packed bf16 pair, round-to-nearest-even (finite inputs)
static __device__ __forceinline__ u32 pk2bf(float f0, float f1) {
    u32 u0 = __float_as_uint(f0);
    u32 u1 = __float_as_uint(f1);
    u0 += 0x7fffu + ((u0 >> 16) & 1u);
    u1 += 0x7fffu + ((u1 >> 16) & 1u);
    return (u0 >> 16) | (u1 & 0xffff0000u);
}

// async 16B-per-lane global->LDS copy; lds dest is wave-uniform base,
// HW writes lane l at base + l*16.
static __device__ __forceinline__ void async_cp16(const float* g, float* l) {
    __builtin_amdgcn_global_load_lds(
        (const __attribute__((address_space(1))) u32*)g,
        (__attribute__((address_space(3))) u32*)l, 16, 0, 0);
}

// ---------------------------------------------------------------------------
// Fused GEMM: wave-autonomous K-streaming through async LDS ring, fp32 A
// converted in-register. Fragment mapping identical to the verified version:
//   B-frag: lane holds B[k = quad*8 + j][n = l15] = W[nbase+l15][k]
//   A-frag: lane holds A[m = l15 (+16)][k = quad*8 + j]
//   C/D:    col = lane&15, row = quad*4 + reg
// ---------------------------------------------------------------------------
__global__ __launch_bounds__(256, 2) void gemm_kernel(
    const float* __restrict__ W, const float* __restrict__ x,
    const float* __restrict__ bias, float* __restrict__ out)
{
    __shared__ float wbuf[4 * 2 * CHFL];   // 4 waves x 2 bufs x 8 KB = 64 KB
    __shared__ float red[4 * 512];         // 8 KB cross-wave reduction

    const int tid  = threadIdx.x;
    const int wave = tid >> 6;
    const int lane = tid & 63;
    const int quad = lane >> 4;
    const int l15  = lane & 15;
    const int rp   = lane >> 5;     // staging: row within pair
    const int slot = lane & 31;     // staging: 16B slot within 512B row
    const int swz  = l15 & 7;       // read-side XOR (matches source-side XOR)

    const int nbase = blockIdx.x * BN;
    const int kw    = wave * WKSLICE;

    const float* wsrc = W + (size_t)nbase * K + kw;
    const float* xa0  = x + (size_t)l15 * K + kw + quad * 8;   // row l15
    const float* xa1  = xa0 + (size_t)16 * K;                  // row l15+16

    float* wb0 = wbuf + wave * (2 * CHFL);   // this wave's 2-buffer ring

    f32x4 acc0 = {0.f, 0.f, 0.f, 0.f};
    f32x4 acc1 = {0.f, 0.f, 0.f, 0.f};

    // Stage chunk c of this wave's K-slice into buffer b (8 x 1KB DMAs).
    // Instruction i covers rows 2i,2i+1; LDS linear, global source carries
    // the XOR so that LDS slot s of row r holds global 16B-chunk (s^(r&7)).
#define STAGE(c, b) do {                                                      \
    _Pragma("unroll")                                                         \
    for (int i = 0; i < 8; ++i) {                                             \
        const int row_ = 2 * i + rp;                                          \
        const float* s_ = wsrc + (size_t)row_ * K + (c) * CK                  \
                          + ((slot ^ (row_ & 7)) << 2);                       \
        async_cp16(s_, wb0 + (b) * CHFL + i * 256);                           \
    }                                                                         \
} while (0)

    // Load this chunk's 16 fp32 A-quarters (global, L2-hot) into registers.
#define LOAD_A(c, L0, H0, L1, H1) do {                                       \
    _Pragma("unroll")                                                         \
    for (int s = 0; s < 4; ++s) {                                             \
        L0[s] = *(const f32x4*)(xa0 + (c) * CK + s * 32);                     \
        H0[s] = *(const f32x4*)(xa0 + (c) * CK + s * 32 + 4);                 \
        L1[s] = *(const f32x4*)(xa1 + (c) * CK + s * 32);                     \
        H1[s] = *(const f32x4*)(xa1 + (c) * CK + s * 32 + 4);                 \
    }                                                                         \
} while (0)

    // 4 k-steps of MFMA from LDS buffer b + in-register A conversion.
#define COMPUTE(b, L0, H0, L1, H1) do {                                       \
    const float* wb_ = wb0 + (b) * CHFL + l15 * CK;                           \
    _Pragma("unroll")                                                         \
    for (int s = 0; s < 4; ++s) {                                             \
        const int c0_ = s * 8 + quad * 2;                                     \
        f32x4 w0 = *(const f32x4*)(wb_ + ((c0_ ^ swz) << 2));                 \
        f32x4 w1 = *(const f32x4*)(wb_ + (((c0_ + 1) ^ swz) << 2));           \
        union { bf16x8 v; u32 u[4]; } bb, aa0, aa1;                           \
        bb.u[0]  = pk2bf(w0.x, w0.y);    bb.u[1]  = pk2bf(w0.z, w0.w);        \
        bb.u[2]  = pk2bf(w1.x, w1.y);    bb.u[3]  = pk2bf(w1.z, w1.w);        \
        aa0.u[0] = pk2bf(L0[s].x, L0[s].y); aa0.u[1] = pk2bf(L0[s].z, L0[s].w);\
        aa0.u[2] = pk2bf(H0[s].x, H0[s].y); aa0.u[3] = pk2bf(H0[s].z, H0[s].w);\
        aa1.u[0] = pk2bf(L1[s].x, L1[s].y); aa1.u[1] = pk2bf(L1[s].z, L1[s].w);\
        aa1.u[2] = pk2bf(H1[s].x, H1[s].y); aa1.u[3] = pk2bf(H1[s].z, H1[s].w);\
        acc0 = __builtin_amdgcn_mfma_f32_16x16x32_bf16(aa0.v, bb.v, acc0,     \
                                                       0, 0, 0);              \
        acc1 = __builtin_amdgcn_mfma_f32_16x16x32_bf16(aa1.v, bb.v, acc1,     \
                                                       0, 0, 0);              \
    }                                                                         \
} while (0)

    f32x4 L0A[4], H0A[4], L1A[4], H1A[4];   // A double-buffer, statically
    f32x4 L0B[4], H0B[4], L1B[4], H1B[4];   // named sets (rule #20)

    // Prologue: queue = [W0(8 DMAs), A0(16 loads)] = 24 vmem ops
    STAGE(0, 0);
    LOAD_A(0, L0A, H0A, L1A, H1A);

    #pragma unroll
    for (int c = 0; c < NCHUNK; ++c) {
        const int b = c & 1;
        if (c + 1 < NCHUNK) {
            STAGE(c + 1, b ^ 1);                         // += 8 DMAs
            if ((c + 1) & 1) LOAD_A(c + 1, L0B, H0B, L1B, H1B);  // += 16
            else             LOAD_A(c + 1, L0A, H0A, L1A, H1A);
            // Oldest 24 of 48 = {Wc, Ac} -> landed; chunk c+1 stays in flight.
            asm volatile("s_waitcnt vmcnt(24)" ::: "memory");
            __builtin_amdgcn_sched_barrier(0);   // pin: nothing hoists above
        } else {
            asm volatile("s_waitcnt vmcnt(0)" ::: "memory");
            __builtin_amdgcn_sched_barrier(0);
        }
        if (b) COMPUTE(b, L0B, H0B, L1B, H1B);
        else   COMPUTE(b, L0A, H0A, L1A, H1A);
    }

#undef STAGE
#undef LOAD_A
#undef COMPUTE

    // partials -> LDS (C/D layout: row = quad*4 + r, col = l15)
    #pragma unroll
    for (int r = 0; r < 4; ++r) {
        red[wave * 512 + (quad * 4 + r) * 16 + l15]      = acc0[r];
        red[wave * 512 + (16 + quad * 4 + r) * 16 + l15] = acc1[r];
    }
    __syncthreads();

    // 512 outputs, 256 threads x 2: sum 4 waves, add bias, store
    for (int e = tid; e < 512; e += 256) {
        float s = red[e] + red[512 + e] + red[1024 + e] + red[1536 + e];
        int m = e >> 4, n = e & 15;
        out[(size_t)m * N + nbase + n] = s + bias[nbase + n];
    }
}

extern "C" void kernel_launch(void* const* d_in, const int* in_sizes, int n_in,
                              void* d_out, int out_size, void* d_ws, size_t ws_size,
                              hipStream_t stream) {
    const float* x    = (const float*)d_in[0];
    const float* W    = (const float*)d_in[1];
    const float* bias = (const float*)d_in[2];
    float* out        = (float*)d_out;
    (void)d_ws; (void)ws_size;   // workspace deliberately unused

    gemm_kernel<<<N / BN, 256, 0, stream>>>(W, x, bias, out);
}

// Round 4
// 256.359 us; speedup vs baseline: 1.0342x; 1.0342x over previous
//
#include <hip/hip_runtime.h>
#include <hip/hip_bf16.h>
#include <stdint.h>

// y = x @ W^T + bias ; x:(32,4096) f32, W:(11008,4096) f32, bias:(11008) f32
//
// SESSION CONCLUSION (rounds 0-3): dur_us = ~220 us fixed harness reset cost
// (unconditional 688 MB workspace-poison fill @ ~105 us + ~56 restore
// dispatches) + ~30-40 us kernel time. The gemm itself is HBM-bound at the
// floor: W (180.4 MB) is streamed exactly once at ~6.9 TB/s (= the fill's
// demonstrated rate) ~= 27-29 us. Evidence: a complete rewrite of the W path
// (async global_load_lds double-buffered LDS ring, counted vmcnt, T2 swizzle)
// measured IDENTICAL to this VGPR-load version (254.6 vs 253.9 us, within
// noise), while a fused fp32-A variant regressed +10 us (2x A cache traffic)
// -- so dur IS sensitive to kernel changes >=10 us; the tie is a real floor.
// Little's law: unroll-4 keeps ~8 dwordx4 in flight/wave = 8 KB/wave
// (16 B/lane x 64 lanes per load) x 2752 waves >> the ~2.4 MB device-wide
// needed to saturate HBM at ~900 cy latency. This is the best-measured
// version (253.9 us), restored.
//
// Structure: 688 blocks, each owns 16 output cols (one 16-wide MFMA N-tile)
// over the FULL K. The 4 waves split K (1024 each), stream W straight from
// global memory to registers in B-fragment layout (8 contiguous floats per
// lane = two dwordx4), convert fp32->bf16 in-register, MFMA-accumulate, then
// cross-wave reduce via LDS. No atomics, no barriers in the K-loop.

#define M 32
#define N 11008
#define K 4096
#define BN 16
#define WKSLICE (K / 4)          // 1024 k per wave
#define KSTEPS (WKSLICE / 32)    // 32 MFMA k-steps per wave

typedef __attribute__((ext_vector_type(8))) short bf16x8;
typedef __attribute__((ext_vector_type(4))) float f32x4;

// two fp32 -> packed bf16 pair, round-to-nearest-even (finite inputs)
static __device__ __forceinline__ unsigned int pk2bf(float f0, float f1) {
    unsigned int u0 = __float_as_uint(f0);
    unsigned int u1 = __float_as_uint(f1);
    u0 += 0x7fffu + ((u0 >> 16) & 1u);
    u1 += 0x7fffu + ((u1 >> 16) & 1u);
    return (u0 >> 16) | (u1 & 0xffff0000u);
}

// ---------------------------------------------------------------------------
// Kernel 1: x fp32 -> bf16 into ws (32*4096 elems = 32768 uint2 of 4 bf16).
// ---------------------------------------------------------------------------
__global__ __launch_bounds__(256) void cvt_kernel(
    const float* __restrict__ x, unsigned short* __restrict__ xbf)
{
    int i = blockIdx.x * 256 + threadIdx.x;          // 128 blocks x 256 = 32768
    f32x4 v = ((const f32x4*)x)[i];
    uint2 o;
    o.x = pk2bf(v.x, v.y);
    o.y = pk2bf(v.z, v.w);
    ((uint2*)xbf)[i] = o;
}

// ---------------------------------------------------------------------------
// Kernel 2: GEMM, wave-autonomous K-streaming.
// B-frag (16x16x32): lane holds B[k = quad*8 + j][n = l15] = W[nbase+l15][k]
//   -> 8 contiguous floats of one W row per lane per k-step.
// A-frag: lane holds A[m = l15 (+16)][k = quad*8 + j] from bf16 x.
// C/D: col = lane&15, row = quad*4 + reg.
// ---------------------------------------------------------------------------
__global__ __launch_bounds__(256) void gemm_kernel(
    const float* __restrict__ W, const unsigned short* __restrict__ xbf,
    const float* __restrict__ bias, float* __restrict__ out)
{
    __shared__ float red[4 * 512];   // 4 waves x (32 m x 16 n) fp32 = 8 KB

    const int tid  = threadIdx.x;
    const int wave = tid >> 6;
    const int lane = tid & 63;
    const int quad = lane >> 4;
    const int l15  = lane & 15;

    const int nbase = blockIdx.x * BN;
    const int kw    = wave * WKSLICE;

    const float*          wrow = W   + (size_t)(nbase + l15) * K + kw + quad * 8;
    const unsigned short* xa0  = xbf + (size_t)l15 * K        + kw + quad * 8;
    const unsigned short* xa1  = xa0 + (size_t)16 * K;

    f32x4 acc0 = {0.f, 0.f, 0.f, 0.f};
    f32x4 acc1 = {0.f, 0.f, 0.f, 0.f};

    #pragma unroll 4
    for (int s = 0; s < KSTEPS; ++s) {
        const int off = s * 32;
        f32x4 w0 = *(const f32x4*)(wrow + off);
        f32x4 w1 = *(const f32x4*)(wrow + off + 4);
        bf16x8 a0 = *(const bf16x8*)(xa0 + off);
        bf16x8 a1 = *(const bf16x8*)(xa1 + off);

        union { bf16x8 v; unsigned int u[4]; } b;
        b.u[0] = pk2bf(w0.x, w0.y);
        b.u[1] = pk2bf(w0.z, w0.w);
        b.u[2] = pk2bf(w1.x, w1.y);
        b.u[3] = pk2bf(w1.z, w1.w);

        acc0 = __builtin_amdgcn_mfma_f32_16x16x32_bf16(a0, b.v, acc0, 0, 0, 0);
        acc1 = __builtin_amdgcn_mfma_f32_16x16x32_bf16(a1, b.v, acc1, 0, 0, 0);
    }

    // partials -> LDS (C/D layout: row = quad*4 + r, col = l15)
    #pragma unroll
    for (int r = 0; r < 4; ++r) {
        red[wave * 512 + (quad * 4 + r) * 16 + l15]        = acc0[r];
        red[wave * 512 + (16 + quad * 4 + r) * 16 + l15]   = acc1[r];
    }
    __syncthreads();

    // 512 outputs, 256 threads x 2: sum 4 waves, add bias, store
    for (int e = tid; e < 512; e += 256) {
        float s = red[e] + red[512 + e] + red[1024 + e] + red[1536 + e];
        int m = e >> 4, n = e & 15;
        out[(size_t)m * N + nbase + n] = s + bias[nbase + n];
    }
}

extern "C" void kernel_launch(void* const* d_in, const int* in_sizes, int n_in,
                              void* d_out, int out_size, void* d_ws, size_t ws_size,
                              hipStream_t stream) {
    const float* x    = (const float*)d_in[0];
    const float* W    = (const float*)d_in[1];
    const float* bias = (const float*)d_in[2];
    float* out        = (float*)d_out;
    unsigned short* xbf = (unsigned short*)d_ws;   // 256 KB

    cvt_kernel<<<(M * K / 4) / 256, 256, 0, stream>>>(x, xbf);
    gemm_kernel<<<N / BN, 256, 0, stream>>>(W, xbf, bias, out);
}